// Round 1
// baseline (788.148 us; speedup 1.0000x reference)
//
#include <hip/hip_runtime.h>
#include <cstdint>
#include <cstddef>

#define BB 16
#define CIN 512
#define NPIX 4096   // 64*64
#define C8 64
#define C2 256
#define MM 1024     // pooled positions 32*32

using bf16x8 = __attribute__((ext_vector_type(8))) short;
using f32x4  = __attribute__((ext_vector_type(4))) float;

__device__ __forceinline__ short f2bf(float f) {
  union { float f; unsigned u; } v; v.f = f;
  unsigned r = v.u + 0x7FFFu + ((v.u >> 16) & 1u);
  return (short)(r >> 16);
}
__device__ __forceinline__ bf16x8 ldg8(const short* p) {
  return *reinterpret_cast<const bf16x8*>(p);
}
__device__ __forceinline__ bf16x8 lds8(const short* p) {  // 8B-aligned LDS read
  union { unsigned long long q[2]; bf16x8 v; } u;
  u.q[0] = *reinterpret_cast<const unsigned long long*>(p);
  u.q[1] = *reinterpret_cast<const unsigned long long*>(p + 4);
  return u.v;
}
#define MFMA(a, b, c) __builtin_amdgcn_mfma_f32_16x16x32_bf16(a, b, c, 0, 0, 0)

// ---------------------------------------------------------------------------
// weight casts: Wtheta(32768) | Wphi(32768) | Wg(131072) | Wo(131072) floats
// ---------------------------------------------------------------------------
__global__ __launch_bounds__(256) void cast_w_k(const float* __restrict__ wa,
                                                const float* __restrict__ wb,
                                                const float* __restrict__ wc,
                                                const float* __restrict__ wd,
                                                short* __restrict__ out) {
  int i = blockIdx.x * 256 + threadIdx.x;
  float v;
  if (i < 32768) v = wa[i];
  else if (i < 65536) v = wb[i - 32768];
  else if (i < 196608) v = wc[i - 65536];
  else v = wd[i - 196608];
  out[i] = f2bf(v);
}

// ---------------------------------------------------------------------------
// conv_mega: x fp32 (B,512,4096) -> thetaT (B,4096,64), phiT (B,1024,64),
//            gp (B,256,1024)   all bf16, relu, phi/g 2x2-maxpooled.
// (unchanged this round)
// ---------------------------------------------------------------------------
__global__ __launch_bounds__(512) void conv_mega_k(
    const float* __restrict__ x, const short* __restrict__ wbf,
    const float* __restrict__ bth, const float* __restrict__ bph,
    const float* __restrict__ bg,
    short* __restrict__ thetaT, short* __restrict__ phiT,
    short* __restrict__ gp) {
  __shared__ __align__(16) short xs[128][36];   // stride 72B: 8B-aligned rows
  const int t = threadIdx.x, w = t >> 6, l = t & 63;
  const int lr = l & 15, quad = l >> 4;
  const int bx = blockIdx.x, b = blockIdx.y;
  const int nbase = bx * 128;
  const float* xb = x + ((size_t)b * CIN << 12) + nbase;

  const int nl = t & 127, cp = t >> 7;

  f32x4 acc[3][8];
#pragma unroll
  for (int i = 0; i < 3; ++i)
#pragma unroll
    for (int j = 0; j < 8; ++j) acc[i][j] = (f32x4){0.f, 0.f, 0.f, 0.f};

  float pv0[4], pv1[4];
#pragma unroll
  for (int p = 0; p < 4; ++p) {
    int cl = (p * 4 + cp) * 2;
    pv0[p] = xb[((size_t)cl << 12) + nl];
    pv1[p] = xb[((size_t)(cl + 1) << 12) + nl];
  }

  for (int c0 = 0; c0 < CIN; c0 += 32) {
    __syncthreads();
#pragma unroll
    for (int p = 0; p < 4; ++p) {
      int cl = (p * 4 + cp) * 2;
      unsigned pk = (unsigned)(unsigned short)f2bf(pv0[p]) |
                    ((unsigned)(unsigned short)f2bf(pv1[p]) << 16);
      *reinterpret_cast<unsigned*>(&xs[nl][cl]) = pk;
    }
    __syncthreads();
    if (c0 + 32 < CIN) {
#pragma unroll
      for (int p = 0; p < 4; ++p) {
        int cl = (p * 4 + cp) * 2;
        pv0[p] = xb[((size_t)(c0 + 32 + cl) << 12) + nl];
        pv1[p] = xb[((size_t)(c0 + 32 + cl + 1) << 12) + nl];
      }
    }
    bf16x8 af[3];
#pragma unroll
    for (int tt = 0; tt < 3; ++tt)
      af[tt] = ldg8(wbf + (size_t)(w * 48 + tt * 16 + lr) * CIN + c0 + quad * 8);
#pragma unroll
    for (int nt = 0; nt < 8; ++nt) {
      bf16x8 bfr = lds8(&xs[nt * 16 + lr][quad * 8]);
#pragma unroll
      for (int tt = 0; tt < 3; ++tt)
        acc[tt][nt] = MFMA(af[tt], bfr, acc[tt][nt]);
    }
  }

#pragma unroll
  for (int tt = 0; tt < 3; ++tt) {
    const int ocb = w * 48 + tt * 16;
    if (ocb < 64) {           // theta: no pool, (n, 64) layout
      short* tb = thetaT + ((size_t)b << 12) * C8;
#pragma unroll
      for (int r = 0; r < 4; ++r) {
        int oc = ocb + quad * 4 + r;
        float bia = bth[oc];
#pragma unroll
        for (int nt = 0; nt < 8; ++nt) {
          int n = nbase + nt * 16 + lr;
          tb[(size_t)n * C8 + oc] = f2bf(fmaxf(acc[tt][nt][r] + bia, 0.f));
        }
      }
    } else if (ocb < 128) {   // phi: pool, (m, 64) layout
      short* pb = phiT + ((size_t)b << 10) * C8;
#pragma unroll
      for (int r = 0; r < 4; ++r) {
        int oc = ocb - 64 + quad * 4 + r;
        float bia = bph[oc];
#pragma unroll
        for (int nt = 0; nt < 4; ++nt) {
          float va = fmaxf(acc[tt][nt][r] + bia, 0.f);
          float vb = fmaxf(acc[tt][nt + 4][r] + bia, 0.f);
          float pa = fmaxf(va, __shfl_xor(va, 1));
          float pbv = fmaxf(vb, __shfl_xor(vb, 1));
          float pool = fmaxf(pa, pbv);
          if ((l & 1) == 0) {
            int m = bx * 32 + nt * 8 + (lr >> 1);
            pb[(size_t)m * C8 + oc] = f2bf(pool);
          }
        }
      }
    } else {                  // g: pool, (256, 1024) c-major layout
      short* gb = gp + ((size_t)b << 10) * C2;
#pragma unroll
      for (int r = 0; r < 4; ++r) {
        int oc = ocb - 128 + quad * 4 + r;
        float bia = bg[oc];
#pragma unroll
        for (int nt = 0; nt < 4; ++nt) {
          float va = fmaxf(acc[tt][nt][r] + bia, 0.f);
          float vb = fmaxf(acc[tt][nt + 4][r] + bia, 0.f);
          float pa = fmaxf(va, __shfl_xor(va, 1));
          float pbv = fmaxf(vb, __shfl_xor(vb, 1));
          float pool = fmaxf(pa, pbv);
          if ((l & 1) == 0) {
            int m = bx * 32 + nt * 8 + (lr >> 1);
            gb[(size_t)oc * MM + m] = f2bf(pool);
          }
        }
      }
    }
  }
}

// ---------------------------------------------------------------------------
// attn_k v2: barrier-free, one wave per block, 16 queries per wave.
// Swapped scores MFMA(phi, theta) -> lane holds S[m][n], n = lane&15, so
// online softmax is per-lane regs + 2 shfl_xor. P transposed through a
// wave-local XOR-swizzled LDS tile (no __syncthreads anywhere). PV covers all
// 256 channels; fused final conv covers all 512 oc for the wave's 16 queries.
// launch_bounds(64,3): VGPR cap ~168 -> 3 waves/SIMD residency.
// ---------------------------------------------------------------------------
__global__ __launch_bounds__(64, 3) void attn_k(
    const short* __restrict__ thetaT, const short* __restrict__ phiT,
    const short* __restrict__ gp, const short* __restrict__ wo,
    const float* __restrict__ bo, const float* __restrict__ x,
    const float* __restrict__ gamma, float* __restrict__ out) {
  __shared__ __align__(16) short buf[16 * 256];   // 8KB: p-chunk (16x128) / o (16x256)
  const int t = threadIdx.x, lr = t & 15, quad = t >> 4;
  const int b = blockIdx.y;
  const int n0 = blockIdx.x * 16;
  char* bufc = reinterpret_cast<char*>(buf);
  const int swz = (lr & 7) << 4;   // XOR-swizzle on 16B granules, keyed by row

  const short* thb = thetaT + ((size_t)b << 12) * C8;
  const short* phb = phiT + ((size_t)b << 10) * C8;
  const short* gpb = gp + ((size_t)b << 10) * C2;

  // theta B-frag for this wave's 16 queries (row n = n0+lr, K=64 split in 2)
  bf16x8 tb0 = ldg8(thb + (size_t)(n0 + lr) * C8 + quad * 8);
  bf16x8 tb1 = ldg8(thb + (size_t)(n0 + lr) * C8 + 32 + quad * 8);

  f32x4 oacc[16];   // o[c = ct*16 + quad*4 + r][n = n0 + lr]
#pragma unroll
  for (int i = 0; i < 16; ++i) oacc[i] = (f32x4){0.f, 0.f, 0.f, 0.f};
  float mrun = -3e38f, ssum = 0.f;

  for (int ch = 0; ch < 8; ++ch) {     // 8 m-chunks of 128
    const int m0 = ch * 128;
    // ---- scores S^T: sacc[mt][r] = S[m0 + mt*16 + quad*4 + r][n0 + lr] ----
    f32x4 sacc[8];
#pragma unroll
    for (int i = 0; i < 8; ++i) sacc[i] = (f32x4){0.f, 0.f, 0.f, 0.f};
#pragma unroll
    for (int mt = 0; mt < 8; ++mt) {
      const short* pr = phb + (size_t)(m0 + mt * 16 + lr) * C8 + quad * 8;
      sacc[mt] = MFMA(ldg8(pr), tb0, sacc[mt]);
      sacc[mt] = MFMA(ldg8(pr + 32), tb1, sacc[mt]);
    }
    // ---- online softmax: per-lane reduce + 2 shfls (lanes lr,lr+16,+32,+48) ----
    float cmax = sacc[0][0];
#pragma unroll
    for (int mt = 0; mt < 8; ++mt) {
      cmax = fmaxf(cmax, fmaxf(fmaxf(sacc[mt][0], sacc[mt][1]),
                               fmaxf(sacc[mt][2], sacc[mt][3])));
    }
    cmax = fmaxf(cmax, __shfl_xor(cmax, 16));
    cmax = fmaxf(cmax, __shfl_xor(cmax, 32));
    float mnew = fmaxf(mrun, cmax);
    float alpha = __expf(mrun - mnew);
    // WAR: previous chunk's p reads must have completed before overwrite
    asm volatile("s_waitcnt lgkmcnt(0)" ::: "memory");
    float rsum = 0.f;
#pragma unroll
    for (int mt = 0; mt < 8; ++mt) {
      float e0 = __expf(sacc[mt][0] - mnew);
      float e1 = __expf(sacc[mt][1] - mnew);
      float e2 = __expf(sacc[mt][2] - mnew);
      float e3 = __expf(sacc[mt][3] - mnew);
      rsum += (e0 + e1) + (e2 + e3);
      short4 pk;
      pk.x = f2bf(e0); pk.y = f2bf(e1); pk.z = f2bf(e2); pk.w = f2bf(e3);
      int byte = lr * 256 + mt * 32 + quad * 8;   // row n=lr (128 shorts), col m-m0
      *reinterpret_cast<short4*>(bufc + (byte ^ swz)) = pk;
    }
    ssum = ssum * alpha + rsum;
    mrun = mnew;
#pragma unroll
    for (int i = 0; i < 16; ++i) oacc[i] *= alpha;
    asm volatile("s_waitcnt lgkmcnt(0)" ::: "memory");   // p visible to reads
    // ---- PV: all 256 channels x this wave's 16 queries ----
#pragma unroll
    for (int kc = 0; kc < 4; ++kc) {
      int byte = lr * 256 + kc * 64 + quad * 16;
      bf16x8 pf = *reinterpret_cast<const bf16x8*>(bufc + (byte ^ swz));
#pragma unroll
      for (int ct = 0; ct < 16; ++ct) {
        bf16x8 ga = ldg8(gpb + (size_t)(ct * 16 + lr) * MM + m0 + kc * 32 + quad * 8);
        oacc[ct] = MFMA(ga, pf, oacc[ct]);
      }
    }
  }

  // ---- softmax denominator (full sum per query n) ----
  ssum += __shfl_xor(ssum, 16);
  ssum += __shfl_xor(ssum, 32);
  const float invn = 1.f / ssum;

  // ---- o -> LDS as (16 n x 256 c), same XOR swizzle ----
  asm volatile("s_waitcnt lgkmcnt(0)" ::: "memory");   // last p reads done
#pragma unroll
  for (int ct = 0; ct < 16; ++ct) {
    short4 pk;
    pk.x = f2bf(oacc[ct][0] * invn);
    pk.y = f2bf(oacc[ct][1] * invn);
    pk.z = f2bf(oacc[ct][2] * invn);
    pk.w = f2bf(oacc[ct][3] * invn);
    int byte = lr * 512 + ct * 32 + quad * 8;   // row n=lr (256 shorts), col c
    *reinterpret_cast<short4*>(bufc + (byte ^ swz)) = pk;
  }
  asm volatile("s_waitcnt lgkmcnt(0)" ::: "memory");   // o visible

  // ---- fused final conv: 4 groups of 128 oc, acc2 = 32 VGPRs/group ----
  const float g0 = gamma[0];
  for (int gI = 0; gI < 4; ++gI) {
    f32x4 acc2[8];
#pragma unroll
    for (int i = 0; i < 8; ++i) acc2[i] = (f32x4){0.f, 0.f, 0.f, 0.f};
#pragma unroll
    for (int kc = 0; kc < 8; ++kc) {
      int byte = lr * 512 + kc * 64 + quad * 16;
      bf16x8 of = *reinterpret_cast<const bf16x8*>(bufc + (byte ^ swz));
#pragma unroll
      for (int ot = 0; ot < 8; ++ot) {
        bf16x8 wa = ldg8(wo + (size_t)(gI * 128 + ot * 16 + lr) * C2 +
                         kc * 32 + quad * 8);
        acc2[ot] = MFMA(wa, of, acc2[ot]);
      }
    }
#pragma unroll
    for (int ot = 0; ot < 8; ++ot) {
#pragma unroll
      for (int r = 0; r < 4; ++r) {
        int oc = gI * 128 + ot * 16 + quad * 4 + r;
        size_t base = ((size_t)(b * CIN + oc) << 12) + n0 + lr;
        float v = g0 * fmaxf(acc2[ot][r] + bo[oc], 0.f);
        out[base] = v + x[base];
      }
    }
  }
}

// ---------------------------------------------------------------------------
extern "C" void kernel_launch(void* const* d_in, const int* in_sizes, int n_in,
                              void* d_out, int out_size, void* d_ws, size_t ws_size,
                              hipStream_t stream) {
  const float* x       = (const float*)d_in[0];
  const float* W_theta = (const float*)d_in[1];
  const float* b_theta = (const float*)d_in[2];
  const float* W_phi   = (const float*)d_in[3];
  const float* b_phi   = (const float*)d_in[4];
  const float* W_g     = (const float*)d_in[5];
  const float* b_g     = (const float*)d_in[6];
  const float* W_o     = (const float*)d_in[7];
  const float* b_o     = (const float*)d_in[8];
  const float* gamma   = (const float*)d_in[9];
  float* out = (float*)d_out;
  char* W = (char*)d_ws;

  // workspace (bytes): thetaT 8,388,608 | phiT 2,097,152 | gp 8,388,608 | wbf 655,360
  short* thetaT = (short*)(W);
  short* phiT   = (short*)(W + 8388608);
  short* gp     = (short*)(W + 10485760);
  short* wbf    = (short*)(W + 18874368);
  short* wo     = wbf + 196608;

  cast_w_k<<<dim3(1280), 256, 0, stream>>>(W_theta, W_phi, W_g, W_o, wbf);
  conv_mega_k<<<dim3(32, 16), 512, 0, stream>>>(x, wbf, b_theta, b_phi, b_g,
                                                thetaT, phiT, gp);
  attn_k<<<dim3(256, 16), 64, 0, stream>>>(thetaT, phiT, gp, wo, b_o, x, gamma, out);
}

// Round 2
// 552.395 us; speedup vs baseline: 1.4268x; 1.4268x over previous
//
#include <hip/hip_runtime.h>
#include <cstdint>
#include <cstddef>

#define BB 16
#define CIN 512
#define NPIX 4096   // 64*64
#define C8 64
#define C2 256
#define MM 1024     // pooled positions 32*32

using bf16x8 = __attribute__((ext_vector_type(8))) short;
using f32x4  = __attribute__((ext_vector_type(4))) float;

__device__ __forceinline__ short f2bf(float f) {
  union { float f; unsigned u; } v; v.f = f;
  unsigned r = v.u + 0x7FFFu + ((v.u >> 16) & 1u);
  return (short)(r >> 16);
}
__device__ __forceinline__ bf16x8 ldg8(const short* p) {
  return *reinterpret_cast<const bf16x8*>(p);
}
__device__ __forceinline__ bf16x8 lds8(const short* p) {  // 8B-aligned LDS read
  union { unsigned long long q[2]; bf16x8 v; } u;
  u.q[0] = *reinterpret_cast<const unsigned long long*>(p);
  u.q[1] = *reinterpret_cast<const unsigned long long*>(p + 4);
  return u.v;
}
#define MFMA(a, b, c) __builtin_amdgcn_mfma_f32_16x16x32_bf16(a, b, c, 0, 0, 0)

// ---------------------------------------------------------------------------
// weight casts: Wtheta(32768) | Wphi(32768) | Wg(131072) | Wo(131072) floats
// ---------------------------------------------------------------------------
__global__ __launch_bounds__(256) void cast_w_k(const float* __restrict__ wa,
                                                const float* __restrict__ wb,
                                                const float* __restrict__ wc,
                                                const float* __restrict__ wd,
                                                short* __restrict__ out) {
  int i = blockIdx.x * 256 + threadIdx.x;
  float v;
  if (i < 32768) v = wa[i];
  else if (i < 65536) v = wb[i - 32768];
  else if (i < 196608) v = wc[i - 65536];
  else v = wd[i - 196608];
  out[i] = f2bf(v);
}

// ---------------------------------------------------------------------------
// conv_mega: x fp32 (B,512,4096) -> thetaT (B,4096,64), phiT (B,1024,64),
//            gp (B,256,1024)   all bf16, relu, phi/g 2x2-maxpooled.
// (unchanged)
// ---------------------------------------------------------------------------
__global__ __launch_bounds__(512) void conv_mega_k(
    const float* __restrict__ x, const short* __restrict__ wbf,
    const float* __restrict__ bth, const float* __restrict__ bph,
    const float* __restrict__ bg,
    short* __restrict__ thetaT, short* __restrict__ phiT,
    short* __restrict__ gp) {
  __shared__ __align__(16) short xs[128][36];   // stride 72B: 8B-aligned rows
  const int t = threadIdx.x, w = t >> 6, l = t & 63;
  const int lr = l & 15, quad = l >> 4;
  const int bx = blockIdx.x, b = blockIdx.y;
  const int nbase = bx * 128;
  const float* xb = x + ((size_t)b * CIN << 12) + nbase;

  const int nl = t & 127, cp = t >> 7;

  f32x4 acc[3][8];
#pragma unroll
  for (int i = 0; i < 3; ++i)
#pragma unroll
    for (int j = 0; j < 8; ++j) acc[i][j] = (f32x4){0.f, 0.f, 0.f, 0.f};

  float pv0[4], pv1[4];
#pragma unroll
  for (int p = 0; p < 4; ++p) {
    int cl = (p * 4 + cp) * 2;
    pv0[p] = xb[((size_t)cl << 12) + nl];
    pv1[p] = xb[((size_t)(cl + 1) << 12) + nl];
  }

  for (int c0 = 0; c0 < CIN; c0 += 32) {
    __syncthreads();
#pragma unroll
    for (int p = 0; p < 4; ++p) {
      int cl = (p * 4 + cp) * 2;
      unsigned pk = (unsigned)(unsigned short)f2bf(pv0[p]) |
                    ((unsigned)(unsigned short)f2bf(pv1[p]) << 16);
      *reinterpret_cast<unsigned*>(&xs[nl][cl]) = pk;
    }
    __syncthreads();
    if (c0 + 32 < CIN) {
#pragma unroll
      for (int p = 0; p < 4; ++p) {
        int cl = (p * 4 + cp) * 2;
        pv0[p] = xb[((size_t)(c0 + 32 + cl) << 12) + nl];
        pv1[p] = xb[((size_t)(c0 + 32 + cl + 1) << 12) + nl];
      }
    }
    bf16x8 af[3];
#pragma unroll
    for (int tt = 0; tt < 3; ++tt)
      af[tt] = ldg8(wbf + (size_t)(w * 48 + tt * 16 + lr) * CIN + c0 + quad * 8);
#pragma unroll
    for (int nt = 0; nt < 8; ++nt) {
      bf16x8 bfr = lds8(&xs[nt * 16 + lr][quad * 8]);
#pragma unroll
      for (int tt = 0; tt < 3; ++tt)
        acc[tt][nt] = MFMA(af[tt], bfr, acc[tt][nt]);
    }
  }

#pragma unroll
  for (int tt = 0; tt < 3; ++tt) {
    const int ocb = w * 48 + tt * 16;
    if (ocb < 64) {           // theta: no pool, (n, 64) layout
      short* tb = thetaT + ((size_t)b << 12) * C8;
#pragma unroll
      for (int r = 0; r < 4; ++r) {
        int oc = ocb + quad * 4 + r;
        float bia = bth[oc];
#pragma unroll
        for (int nt = 0; nt < 8; ++nt) {
          int n = nbase + nt * 16 + lr;
          tb[(size_t)n * C8 + oc] = f2bf(fmaxf(acc[tt][nt][r] + bia, 0.f));
        }
      }
    } else if (ocb < 128) {   // phi: pool, (m, 64) layout
      short* pb = phiT + ((size_t)b << 10) * C8;
#pragma unroll
      for (int r = 0; r < 4; ++r) {
        int oc = ocb - 64 + quad * 4 + r;
        float bia = bph[oc];
#pragma unroll
        for (int nt = 0; nt < 4; ++nt) {
          float va = fmaxf(acc[tt][nt][r] + bia, 0.f);
          float vb = fmaxf(acc[tt][nt + 4][r] + bia, 0.f);
          float pa = fmaxf(va, __shfl_xor(va, 1));
          float pbv = fmaxf(vb, __shfl_xor(vb, 1));
          float pool = fmaxf(pa, pbv);
          if ((l & 1) == 0) {
            int m = bx * 32 + nt * 8 + (lr >> 1);
            pb[(size_t)m * C8 + oc] = f2bf(pool);
          }
        }
      }
    } else {                  // g: pool, (256, 1024) c-major layout
      short* gb = gp + ((size_t)b << 10) * C2;
#pragma unroll
      for (int r = 0; r < 4; ++r) {
        int oc = ocb - 128 + quad * 4 + r;
        float bia = bg[oc];
#pragma unroll
        for (int nt = 0; nt < 4; ++nt) {
          float va = fmaxf(acc[tt][nt][r] + bia, 0.f);
          float vb = fmaxf(acc[tt][nt + 4][r] + bia, 0.f);
          float pa = fmaxf(va, __shfl_xor(va, 1));
          float pbv = fmaxf(vb, __shfl_xor(vb, 1));
          float pool = fmaxf(pa, pbv);
          if ((l & 1) == 0) {
            int m = bx * 32 + nt * 8 + (lr >> 1);
            gb[(size_t)oc * MM + m] = f2bf(pool);
          }
        }
      }
    }
  }
}

// ---------------------------------------------------------------------------
// attn_k v3: 4 waves / 64 queries per block (round-0 sharing), software-
// pipelined chunk loop (round-1 latency structure).
//  - wave w computes swapped scores MFMA(phi, theta) for its 16 queries:
//    lane holds S[m][n=lr] -> per-lane softmax + 2 shfl_xor, packed short4
//    P writes, lane-local alpha.
//  - ps double-buffered (2 x 4 x 16 x 132) -> ONE barrier per 128-m chunk;
//    scores(ch+1) issued inside the barrier-free PV(ch) region so phi-loads
//    and ga-loads are in flight together.
//  - PV channel-split: wave w covers c [64w,64w+64) for all 64 queries
//    (ga loads amortized 4x vs round-1), ga[4] batched before MFMA group.
//  - fused final conv in 4 passes of 32 oc (acc2 = 32 VGPR) -> register peak
//    lives in the main loop; __launch_bounds__(256,3) -> 3 blocks/CU.
// ---------------------------------------------------------------------------
__global__ __launch_bounds__(256, 3) void attn_k(
    const short* __restrict__ thetaT, const short* __restrict__ phiT,
    const short* __restrict__ gp, const short* __restrict__ wo,
    const float* __restrict__ bo, const float* __restrict__ x,
    const float* __restrict__ gamma, float* __restrict__ out) {
  // ps[2][4][16][132] (33792B) unioned with os[64][264] (33792B)
  __shared__ __align__(16) short smem[16896];
  __shared__ float balpha[2][4][16];
  __shared__ float binv[4][16];
  const int t = threadIdx.x, w = t >> 6, l = t & 63;
  const int lr = l & 15, quad = l >> 4;
  const int b = blockIdx.y, q0 = blockIdx.x * 64, nw = q0 + w * 16;

  const short* thb = thetaT + ((size_t)b << 12) * C8;
  const short* phb = phiT + ((size_t)b << 10) * C8;
  const short* gpb = gp + ((size_t)b << 10) * C2;

  // theta B-frags for this wave's 16 queries (row n = nw+lr, K=64 in 2 halves)
  bf16x8 tb0 = ldg8(thb + (size_t)(nw + lr) * C8 + quad * 8);
  bf16x8 tb1 = ldg8(thb + (size_t)(nw + lr) * C8 + 32 + quad * 8);

  f32x4 oacc[4][4];   // [ct][qt]: c = 64w+16ct+quad*4+r, n = q0+16qt+lr
#pragma unroll
  for (int i = 0; i < 4; ++i)
#pragma unroll
    for (int j = 0; j < 4; ++j) oacc[i][j] = (f32x4){0.f, 0.f, 0.f, 0.f};
  float mrun = -3e38f, ssum = 0.f;

  // scores+softmax for chunk ch -> ps[ch&1] quadrant w, balpha[ch&1][w]
  auto scores = [&](int ch) {
    const int m0 = ch * 128, buf = ch & 1;
    f32x4 sacc[8];
#pragma unroll
    for (int i = 0; i < 8; ++i) sacc[i] = (f32x4){0.f, 0.f, 0.f, 0.f};
#pragma unroll
    for (int mt = 0; mt < 8; ++mt) {
      const short* pr = phb + (size_t)(m0 + mt * 16 + lr) * C8 + quad * 8;
      sacc[mt] = MFMA(ldg8(pr), tb0, sacc[mt]);
      sacc[mt] = MFMA(ldg8(pr + 32), tb1, sacc[mt]);
    }
    float cmax = sacc[0][0];
#pragma unroll
    for (int mt = 0; mt < 8; ++mt)
      cmax = fmaxf(cmax, fmaxf(fmaxf(sacc[mt][0], sacc[mt][1]),
                               fmaxf(sacc[mt][2], sacc[mt][3])));
    cmax = fmaxf(cmax, __shfl_xor(cmax, 16));
    cmax = fmaxf(cmax, __shfl_xor(cmax, 32));
    const float mnew = fmaxf(mrun, cmax);
    const float al = __expf(mrun - mnew);
    mrun = mnew;
    float rsum = 0.f;
    short* prow = smem + ((((buf << 2) | w) << 4) + lr) * 132;
#pragma unroll
    for (int mt = 0; mt < 8; ++mt) {
      float e0 = __expf(sacc[mt][0] - mnew);
      float e1 = __expf(sacc[mt][1] - mnew);
      float e2 = __expf(sacc[mt][2] - mnew);
      float e3 = __expf(sacc[mt][3] - mnew);
      rsum += (e0 + e1) + (e2 + e3);
      short4 pk;
      pk.x = f2bf(e0); pk.y = f2bf(e1); pk.z = f2bf(e2); pk.w = f2bf(e3);
      *reinterpret_cast<short4*>(prow + mt * 16 + quad * 4) = pk;
    }
    ssum = ssum * al + rsum;
    if (quad == 0) balpha[buf][w][lr] = al;
  };

  scores(0);
  for (int ch = 0; ch < 8; ++ch) {
    const int buf = ch & 1, m0 = ch * 128;
    __syncthreads();   // ps[buf]+balpha[buf] ready; old reads of ps[buf] done
    float av[4];
#pragma unroll
    for (int qt = 0; qt < 4; ++qt) av[qt] = balpha[buf][qt][lr];
#pragma unroll
    for (int ct = 0; ct < 4; ++ct)
#pragma unroll
      for (int qt = 0; qt < 4; ++qt) oacc[ct][qt] *= av[qt];
    // PV: wave w covers c [64w, 64w+64), all 64 queries
#pragma unroll
    for (int kc = 0; kc < 4; ++kc) {
      bf16x8 ga[4];
#pragma unroll
      for (int ct = 0; ct < 4; ++ct)
        ga[ct] = ldg8(gpb + (size_t)(w * 64 + ct * 16 + lr) * MM +
                      m0 + kc * 32 + quad * 8);
      bf16x8 pf[4];
#pragma unroll
      for (int qt = 0; qt < 4; ++qt)
        pf[qt] = lds8(smem + ((((buf << 2) | qt) << 4) + lr) * 132 +
                      kc * 32 + quad * 8);
#pragma unroll
      for (int ct = 0; ct < 4; ++ct)
#pragma unroll
        for (int qt = 0; qt < 4; ++qt)
          oacc[ct][qt] = MFMA(ga[ct], pf[qt], oacc[ct][qt]);
    }
    if (ch < 7) scores(ch + 1);   // fills ps[!buf]; overlaps PV loads above
  }

  // ---- final softmax denominators (sum across the 4 quads sharing n) ----
  ssum += __shfl_xor(ssum, 16);
  ssum += __shfl_xor(ssum, 32);
  if (quad == 0) binv[w][lr] = 1.f / ssum;
  __syncthreads();   // all PV/scores done (smem reusable as os), binv ready
  float invn[4];
#pragma unroll
  for (int qt = 0; qt < 4; ++qt) invn[qt] = binv[qt][lr];

  // ---- write o to LDS as (64 n x 256 c), rows n-local = 16qt+lr ----
  short (*os)[264] = reinterpret_cast<short (*)[264]>(smem);
#pragma unroll
  for (int ct = 0; ct < 4; ++ct) {
    int c0 = w * 64 + ct * 16 + quad * 4;
#pragma unroll
    for (int qt = 0; qt < 4; ++qt) {
      short4 pk;
      pk.x = f2bf(oacc[ct][qt][0] * invn[qt]);
      pk.y = f2bf(oacc[ct][qt][1] * invn[qt]);
      pk.z = f2bf(oacc[ct][qt][2] * invn[qt]);
      pk.w = f2bf(oacc[ct][qt][3] * invn[qt]);
      *reinterpret_cast<short4*>(&os[qt * 16 + lr][c0]) = pk;
    }
  }
  __syncthreads();   // os complete

  // ---- fused final conv: wave w -> oc [128w,+128) in 4 passes of 32 ----
  const float g0 = gamma[0];
  for (int pp = 0; pp < 4; ++pp) {
    const int ocb = w * 128 + pp * 32;
    f32x4 acc2[2][4];
#pragma unroll
    for (int i = 0; i < 2; ++i)
#pragma unroll
      for (int j = 0; j < 4; ++j) acc2[i][j] = (f32x4){0.f, 0.f, 0.f, 0.f};
#pragma unroll
    for (int kc = 0; kc < 8; ++kc) {
      bf16x8 wa[2];
#pragma unroll
      for (int ot = 0; ot < 2; ++ot)
        wa[ot] = ldg8(wo + (size_t)(ocb + ot * 16 + lr) * C2 +
                      kc * 32 + quad * 8);
      bf16x8 of[4];
#pragma unroll
      for (int qt = 0; qt < 4; ++qt)
        of[qt] = lds8(&os[qt * 16 + lr][kc * 32 + quad * 8]);
#pragma unroll
      for (int ot = 0; ot < 2; ++ot)
#pragma unroll
        for (int qt = 0; qt < 4; ++qt)
          acc2[ot][qt] = MFMA(wa[ot], of[qt], acc2[ot][qt]);
    }
#pragma unroll
    for (int ot = 0; ot < 2; ++ot) {
#pragma unroll
      for (int r = 0; r < 4; ++r) {
        int oc = ocb + ot * 16 + quad * 4 + r;
        float bia = bo[oc];
        size_t base = ((size_t)(b * CIN + oc) << 12);
#pragma unroll
        for (int qt = 0; qt < 4; ++qt) {
          int n = q0 + qt * 16 + lr;
          float v = g0 * fmaxf(acc2[ot][qt][r] + bia, 0.f);
          out[base + n] = v + x[base + n];
        }
      }
    }
  }
}

// ---------------------------------------------------------------------------
extern "C" void kernel_launch(void* const* d_in, const int* in_sizes, int n_in,
                              void* d_out, int out_size, void* d_ws, size_t ws_size,
                              hipStream_t stream) {
  const float* x       = (const float*)d_in[0];
  const float* W_theta = (const float*)d_in[1];
  const float* b_theta = (const float*)d_in[2];
  const float* W_phi   = (const float*)d_in[3];
  const float* b_phi   = (const float*)d_in[4];
  const float* W_g     = (const float*)d_in[5];
  const float* b_g     = (const float*)d_in[6];
  const float* W_o     = (const float*)d_in[7];
  const float* b_o     = (const float*)d_in[8];
  const float* gamma   = (const float*)d_in[9];
  float* out = (float*)d_out;
  char* W = (char*)d_ws;

  // workspace (bytes): thetaT 8,388,608 | phiT 2,097,152 | gp 8,388,608 | wbf 655,360
  short* thetaT = (short*)(W);
  short* phiT   = (short*)(W + 8388608);
  short* gp     = (short*)(W + 10485760);
  short* wbf    = (short*)(W + 18874368);
  short* wo     = wbf + 196608;

  cast_w_k<<<dim3(1280), 256, 0, stream>>>(W_theta, W_phi, W_g, W_o, wbf);
  conv_mega_k<<<dim3(32, 16), 512, 0, stream>>>(x, wbf, b_theta, b_phi, b_g,
                                                thetaT, phiT, gp);
  attn_k<<<dim3(64, 16), 256, 0, stream>>>(thetaT, phiT, gp, wo, b_o, x, gamma, out);
}

// Round 3
// 545.034 us; speedup vs baseline: 1.4461x; 1.0135x over previous
//
#include <hip/hip_runtime.h>
#include <cstdint>
#include <cstddef>

#define BB 16
#define CIN 512
#define NPIX 4096   // 64*64
#define C8 64
#define C2 256
#define MM 1024     // pooled positions 32*32

using bf16x8 = __attribute__((ext_vector_type(8))) short;
using f32x4  = __attribute__((ext_vector_type(4))) float;

__device__ __forceinline__ short f2bf(float f) {
  union { float f; unsigned u; } v; v.f = f;
  unsigned r = v.u + 0x7FFFu + ((v.u >> 16) & 1u);
  return (short)(r >> 16);
}
// packed f32x2 -> bf16x2 (RNE), single HW instr on gfx950
__device__ __forceinline__ unsigned cvtpk(float lo, float hi) {
  unsigned r;
  asm("v_cvt_pk_bf16_f32 %0, %1, %2" : "=v"(r) : "v"(lo), "v"(hi));
  return r;
}
__device__ __forceinline__ bf16x8 ldg8(const short* p) {
  return *reinterpret_cast<const bf16x8*>(p);
}
__device__ __forceinline__ bf16x8 lds8(const short* p) {  // 8B-aligned LDS read
  union { unsigned long long q[2]; bf16x8 v; } u;
  u.q[0] = *reinterpret_cast<const unsigned long long*>(p);
  u.q[1] = *reinterpret_cast<const unsigned long long*>(p + 4);
  return u.v;
}
#define MFMA(a, b, c) __builtin_amdgcn_mfma_f32_16x16x32_bf16(a, b, c, 0, 0, 0)
#define LOG2E 1.4426950408889634f

// ---------------------------------------------------------------------------
// weight casts: Wtheta(32768) | Wphi(32768) | Wg(131072) | Wo(131072) floats
// Wtheta pre-scaled by log2(e) so softmax can use raw exp2 (v_exp_f32).
// ---------------------------------------------------------------------------
__global__ __launch_bounds__(256) void cast_w_k(const float* __restrict__ wa,
                                                const float* __restrict__ wb,
                                                const float* __restrict__ wc,
                                                const float* __restrict__ wd,
                                                short* __restrict__ out) {
  int i = blockIdx.x * 256 + threadIdx.x;
  float v;
  if (i < 32768) v = wa[i] * LOG2E;
  else if (i < 65536) v = wb[i - 32768];
  else if (i < 196608) v = wc[i - 65536];
  else v = wd[i - 196608];
  out[i] = f2bf(v);
}

// ---------------------------------------------------------------------------
// conv_mega: x fp32 (B,512,4096) -> thetaT (B,4096,64), phiT (B,1024,64),
//            gp (B,256,1024)   all bf16, relu, phi/g 2x2-maxpooled.
// v4: raw barriers (lgkmcnt-only drain) so the x register-prefetch spans
// chunks (vmcnt never force-drained); wbf af loads issued pre-barrier so
// their latency hides under staging; cvtpk staging pack; nt x loads.
// theta epilogue scales by log2(e) via pre-scaled bias.
// ---------------------------------------------------------------------------
__global__ __launch_bounds__(512) void conv_mega_k(
    const float* __restrict__ x, const short* __restrict__ wbf,
    const float* __restrict__ bth, const float* __restrict__ bph,
    const float* __restrict__ bg,
    short* __restrict__ thetaT, short* __restrict__ phiT,
    short* __restrict__ gp) {
  __shared__ __align__(16) short xs[128][36];   // stride 72B: 8B-aligned rows
  const int t = threadIdx.x, w = t >> 6, l = t & 63;
  const int lr = l & 15, quad = l >> 4;
  const int bx = blockIdx.x, b = blockIdx.y;
  const int nbase = bx * 128;
  const float* xb = x + ((size_t)b * CIN << 12) + nbase;

  const int nl = t & 127, cp = t >> 7;

  f32x4 acc[3][8];
#pragma unroll
  for (int i = 0; i < 3; ++i)
#pragma unroll
    for (int j = 0; j < 8; ++j) acc[i][j] = (f32x4){0.f, 0.f, 0.f, 0.f};

  float pv0[4], pv1[4];
#pragma unroll
  for (int p = 0; p < 4; ++p) {
    int cl = (p * 4 + cp) * 2;
    pv0[p] = __builtin_nontemporal_load(&xb[((size_t)cl << 12) + nl]);
    pv1[p] = __builtin_nontemporal_load(&xb[((size_t)(cl + 1) << 12) + nl]);
  }

  for (int c0 = 0; c0 < CIN; c0 += 32) {
    // issue weight loads early: latency hides under barrier+staging
    bf16x8 af[3];
#pragma unroll
    for (int tt = 0; tt < 3; ++tt)
      af[tt] = ldg8(wbf + (size_t)(w * 48 + tt * 16 + lr) * CIN + c0 + quad * 8);
    asm volatile("s_waitcnt lgkmcnt(0)" ::: "memory");
    __builtin_amdgcn_s_barrier();   // prev chunk's LDS reads complete (WAR)
#pragma unroll
    for (int p = 0; p < 4; ++p) {
      int cl = (p * 4 + cp) * 2;
      *reinterpret_cast<unsigned*>(&xs[nl][cl]) = cvtpk(pv0[p], pv1[p]);
    }
    asm volatile("s_waitcnt lgkmcnt(0)" ::: "memory");
    __builtin_amdgcn_s_barrier();   // xs visible
    if (c0 + 32 < CIN) {
#pragma unroll
      for (int p = 0; p < 4; ++p) {
        int cl = (p * 4 + cp) * 2;
        pv0[p] = __builtin_nontemporal_load(&xb[((size_t)(c0 + 32 + cl) << 12) + nl]);
        pv1[p] = __builtin_nontemporal_load(&xb[((size_t)(c0 + 32 + cl + 1) << 12) + nl]);
      }
    }
#pragma unroll
    for (int nt = 0; nt < 8; ++nt) {
      bf16x8 bfr = lds8(&xs[nt * 16 + lr][quad * 8]);
#pragma unroll
      for (int tt = 0; tt < 3; ++tt)
        acc[tt][nt] = MFMA(af[tt], bfr, acc[tt][nt]);
    }
  }

#pragma unroll
  for (int tt = 0; tt < 3; ++tt) {
    const int ocb = w * 48 + tt * 16;
    if (ocb < 64) {           // theta: no pool, (n, 64) layout, scaled by log2e
      short* tb = thetaT + ((size_t)b << 12) * C8;
#pragma unroll
      for (int r = 0; r < 4; ++r) {
        int oc = ocb + quad * 4 + r;
        float bia = bth[oc] * LOG2E;
#pragma unroll
        for (int nt = 0; nt < 8; ++nt) {
          int n = nbase + nt * 16 + lr;
          tb[(size_t)n * C8 + oc] = f2bf(fmaxf(acc[tt][nt][r] + bia, 0.f));
        }
      }
    } else if (ocb < 128) {   // phi: pool, (m, 64) layout
      short* pb = phiT + ((size_t)b << 10) * C8;
#pragma unroll
      for (int r = 0; r < 4; ++r) {
        int oc = ocb - 64 + quad * 4 + r;
        float bia = bph[oc];
#pragma unroll
        for (int nt = 0; nt < 4; ++nt) {
          float va = fmaxf(acc[tt][nt][r] + bia, 0.f);
          float vb = fmaxf(acc[tt][nt + 4][r] + bia, 0.f);
          float pa = fmaxf(va, __shfl_xor(va, 1));
          float pbv = fmaxf(vb, __shfl_xor(vb, 1));
          float pool = fmaxf(pa, pbv);
          if ((l & 1) == 0) {
            int m = bx * 32 + nt * 8 + (lr >> 1);
            pb[(size_t)m * C8 + oc] = f2bf(pool);
          }
        }
      }
    } else {                  // g: pool, (256, 1024) c-major layout
      short* gb = gp + ((size_t)b << 10) * C2;
#pragma unroll
      for (int r = 0; r < 4; ++r) {
        int oc = ocb - 128 + quad * 4 + r;
        float bia = bg[oc];
#pragma unroll
        for (int nt = 0; nt < 4; ++nt) {
          float va = fmaxf(acc[tt][nt][r] + bia, 0.f);
          float vb = fmaxf(acc[tt][nt + 4][r] + bia, 0.f);
          float pa = fmaxf(va, __shfl_xor(va, 1));
          float pbv = fmaxf(vb, __shfl_xor(vb, 1));
          float pool = fmaxf(pa, pbv);
          if ((l & 1) == 0) {
            int m = bx * 32 + nt * 8 + (lr >> 1);
            gb[(size_t)oc * MM + m] = f2bf(pool);
          }
        }
      }
    }
  }
}

// ---------------------------------------------------------------------------
// attn_k v4: v3 structure + (a) XCD-locality swizzle: 1D grid, b = 2*(blk%8)
// + ((blk>>3)&1) so each XCD serves exactly 2 batches -> phi/gp/theta/wo hot
// set ~2.5MB fits the 4MB per-XCD L2; (b) raw s_barrier with lgkmcnt-only
// drain + kc0 ga register prefetch issued pre-barrier (loads span the
// barrier); (c) exp2-domain softmax (theta pre-scaled), cvtpk packing;
// (d) nontemporal x/out streaming so residual traffic doesn't evict L2.
// ---------------------------------------------------------------------------
__global__ __launch_bounds__(256, 3) void attn_k(
    const short* __restrict__ thetaT, const short* __restrict__ phiT,
    const short* __restrict__ gp, const short* __restrict__ wo,
    const float* __restrict__ bo, const float* __restrict__ x,
    const float* __restrict__ gamma, float* __restrict__ out) {
  // ps[2][4][16][132] (33792B) unioned with os[64][264] (33792B)
  __shared__ __align__(16) short smem[16896];
  __shared__ float balpha[2][4][16];
  __shared__ float binv[4][16];
  const int t = threadIdx.x, w = t >> 6, l = t & 63;
  const int lr = l & 15, quad = l >> 4;
  const int blk = blockIdx.x;
  const int b = ((blk & 7) << 1) | ((blk >> 3) & 1);   // 2 batches per XCD
  const int q0 = (blk >> 4) << 6;
  const int nw = q0 + w * 16;

  const short* thb = thetaT + ((size_t)b << 12) * C8;
  const short* phb = phiT + ((size_t)b << 10) * C8;
  const short* gpb = gp + ((size_t)b << 10) * C2;

  bf16x8 tb0 = ldg8(thb + (size_t)(nw + lr) * C8 + quad * 8);
  bf16x8 tb1 = ldg8(thb + (size_t)(nw + lr) * C8 + 32 + quad * 8);

  f32x4 oacc[4][4];   // [ct][qt]: c = 64w+16ct+quad*4+r, n = q0+16qt+lr
#pragma unroll
  for (int i = 0; i < 4; ++i)
#pragma unroll
    for (int j = 0; j < 4; ++j) oacc[i][j] = (f32x4){0.f, 0.f, 0.f, 0.f};
  float mrun = -3e38f, ssum = 0.f;

  // scores+softmax for chunk ch -> ps[ch&1] quadrant w, balpha[ch&1][w]
  auto scores = [&](int ch) {
    const int m0 = ch * 128, buf = ch & 1;
    f32x4 sacc[8];
#pragma unroll
    for (int i = 0; i < 8; ++i) sacc[i] = (f32x4){0.f, 0.f, 0.f, 0.f};
#pragma unroll
    for (int mt = 0; mt < 8; ++mt) {
      const short* pr = phb + (size_t)(m0 + mt * 16 + lr) * C8 + quad * 8;
      sacc[mt] = MFMA(ldg8(pr), tb0, sacc[mt]);
      sacc[mt] = MFMA(ldg8(pr + 32), tb1, sacc[mt]);
    }
    float cmax = sacc[0][0];
#pragma unroll
    for (int mt = 0; mt < 8; ++mt)
      cmax = fmaxf(cmax, fmaxf(fmaxf(sacc[mt][0], sacc[mt][1]),
                               fmaxf(sacc[mt][2], sacc[mt][3])));
    cmax = fmaxf(cmax, __shfl_xor(cmax, 16));
    cmax = fmaxf(cmax, __shfl_xor(cmax, 32));
    const float mnew = fmaxf(mrun, cmax);
    const float al = exp2f(mrun - mnew);   // exp2 domain (theta pre-scaled)
    mrun = mnew;
    float rsum = 0.f;
    short* prow = smem + ((((buf << 2) | w) << 4) + lr) * 132;
#pragma unroll
    for (int mt = 0; mt < 8; ++mt) {
      float e0 = exp2f(sacc[mt][0] - mnew);
      float e1 = exp2f(sacc[mt][1] - mnew);
      float e2 = exp2f(sacc[mt][2] - mnew);
      float e3 = exp2f(sacc[mt][3] - mnew);
      rsum += (e0 + e1) + (e2 + e3);
      uint2 pk2;
      pk2.x = cvtpk(e0, e1);
      pk2.y = cvtpk(e2, e3);
      *reinterpret_cast<uint2*>(prow + mt * 16 + quad * 4) = pk2;
    }
    ssum = ssum * al + rsum;
    if (quad == 0) balpha[buf][w][lr] = al;
  };

  bf16x8 gpf[4];   // kc0 ga prefetch: issued pre-barrier, consumed post
  auto pfga = [&](int ch) {
    const int m0 = ch * 128;
#pragma unroll
    for (int ct = 0; ct < 4; ++ct)
      gpf[ct] = ldg8(gpb + (size_t)(w * 64 + ct * 16 + lr) * MM + m0 + quad * 8);
  };

  scores(0);
  pfga(0);
  for (int ch = 0; ch < 8; ++ch) {
    const int buf = ch & 1, m0 = ch * 128;
    // raw barrier: drain LDS only; global loads (gpf) stay in flight
    asm volatile("s_waitcnt lgkmcnt(0)" ::: "memory");
    __builtin_amdgcn_s_barrier();
    float av[4];
#pragma unroll
    for (int qt = 0; qt < 4; ++qt) av[qt] = balpha[buf][qt][lr];
#pragma unroll
    for (int ct = 0; ct < 4; ++ct)
#pragma unroll
      for (int qt = 0; qt < 4; ++qt) oacc[ct][qt] *= av[qt];
    // PV kc=0 from prefetched ga
    {
      bf16x8 pf[4];
#pragma unroll
      for (int qt = 0; qt < 4; ++qt)
        pf[qt] = lds8(smem + ((((buf << 2) | qt) << 4) + lr) * 132 + quad * 8);
#pragma unroll
      for (int ct = 0; ct < 4; ++ct)
#pragma unroll
        for (int qt = 0; qt < 4; ++qt)
          oacc[ct][qt] = MFMA(gpf[ct], pf[qt], oacc[ct][qt]);
    }
    // PV kc=1..3 direct
#pragma unroll
    for (int kc = 1; kc < 4; ++kc) {
      bf16x8 ga[4];
#pragma unroll
      for (int ct = 0; ct < 4; ++ct)
        ga[ct] = ldg8(gpb + (size_t)(w * 64 + ct * 16 + lr) * MM +
                      m0 + kc * 32 + quad * 8);
      bf16x8 pf[4];
#pragma unroll
      for (int qt = 0; qt < 4; ++qt)
        pf[qt] = lds8(smem + ((((buf << 2) | qt) << 4) + lr) * 132 +
                      kc * 32 + quad * 8);
#pragma unroll
      for (int ct = 0; ct < 4; ++ct)
#pragma unroll
        for (int qt = 0; qt < 4; ++qt)
          oacc[ct][qt] = MFMA(ga[ct], pf[qt], oacc[ct][qt]);
    }
    if (ch < 7) {
      scores(ch + 1);   // fills ps[!buf]; phi loads overlap PV above
      pfga(ch + 1);     // issued pre-barrier -> spans the raw barrier
    }
  }

  // ---- final softmax denominators ----
  ssum += __shfl_xor(ssum, 16);
  ssum += __shfl_xor(ssum, 32);
  if (quad == 0) binv[w][lr] = 1.f / ssum;
  __syncthreads();   // all PV/scores done (smem reusable as os), binv ready
  float invn[4];
#pragma unroll
  for (int qt = 0; qt < 4; ++qt) invn[qt] = binv[qt][lr];

  // ---- write o to LDS as (64 n x 256 c), rows n-local = 16qt+lr ----
  short (*os)[264] = reinterpret_cast<short (*)[264]>(smem);
#pragma unroll
  for (int ct = 0; ct < 4; ++ct) {
    int c0 = w * 64 + ct * 16 + quad * 4;
#pragma unroll
    for (int qt = 0; qt < 4; ++qt) {
      uint2 pk2;
      pk2.x = cvtpk(oacc[ct][qt][0] * invn[qt], oacc[ct][qt][1] * invn[qt]);
      pk2.y = cvtpk(oacc[ct][qt][2] * invn[qt], oacc[ct][qt][3] * invn[qt]);
      *reinterpret_cast<uint2*>(&os[qt * 16 + lr][c0]) = pk2;
    }
  }
  __syncthreads();   // os complete

  // ---- fused final conv: wave w -> oc [128w,+128) in 4 passes of 32 ----
  const float g0 = gamma[0];
  for (int pp = 0; pp < 4; ++pp) {
    const int ocb = w * 128 + pp * 32;
    f32x4 acc2[2][4];
#pragma unroll
    for (int i = 0; i < 2; ++i)
#pragma unroll
      for (int j = 0; j < 4; ++j) acc2[i][j] = (f32x4){0.f, 0.f, 0.f, 0.f};
#pragma unroll
    for (int kc = 0; kc < 8; ++kc) {
      bf16x8 wa[2];
#pragma unroll
      for (int ot = 0; ot < 2; ++ot)
        wa[ot] = ldg8(wo + (size_t)(ocb + ot * 16 + lr) * C2 +
                      kc * 32 + quad * 8);
      bf16x8 of[4];
#pragma unroll
      for (int qt = 0; qt < 4; ++qt)
        of[qt] = lds8(&os[qt * 16 + lr][kc * 32 + quad * 8]);
#pragma unroll
      for (int ot = 0; ot < 2; ++ot)
#pragma unroll
        for (int qt = 0; qt < 4; ++qt)
          acc2[ot][qt] = MFMA(wa[ot], of[qt], acc2[ot][qt]);
    }
#pragma unroll
    for (int ot = 0; ot < 2; ++ot) {
#pragma unroll
      for (int r = 0; r < 4; ++r) {
        int oc = ocb + ot * 16 + quad * 4 + r;
        float bia = bo[oc];
        size_t base = ((size_t)(b * CIN + oc) << 12);
#pragma unroll
        for (int qt = 0; qt < 4; ++qt) {
          int n = q0 + qt * 16 + lr;
          float xres = __builtin_nontemporal_load(&x[base + n]);
          float v = g0 * fmaxf(acc2[ot][qt][r] + bia, 0.f) + xres;
          __builtin_nontemporal_store(v, &out[base + n]);
        }
      }
    }
  }
}

// ---------------------------------------------------------------------------
extern "C" void kernel_launch(void* const* d_in, const int* in_sizes, int n_in,
                              void* d_out, int out_size, void* d_ws, size_t ws_size,
                              hipStream_t stream) {
  const float* x       = (const float*)d_in[0];
  const float* W_theta = (const float*)d_in[1];
  const float* b_theta = (const float*)d_in[2];
  const float* W_phi   = (const float*)d_in[3];
  const float* b_phi   = (const float*)d_in[4];
  const float* W_g     = (const float*)d_in[5];
  const float* b_g     = (const float*)d_in[6];
  const float* W_o     = (const float*)d_in[7];
  const float* b_o     = (const float*)d_in[8];
  const float* gamma   = (const float*)d_in[9];
  float* out = (float*)d_out;
  char* W = (char*)d_ws;

  // workspace (bytes): thetaT 8,388,608 | phiT 2,097,152 | gp 8,388,608 | wbf 655,360
  short* thetaT = (short*)(W);
  short* phiT   = (short*)(W + 8388608);
  short* gp     = (short*)(W + 10485760);
  short* wbf    = (short*)(W + 18874368);
  short* wo     = wbf + 196608;

  cast_w_k<<<dim3(1280), 256, 0, stream>>>(W_theta, W_phi, W_g, W_o, wbf);
  conv_mega_k<<<dim3(32, 16), 512, 0, stream>>>(x, wbf, b_theta, b_phi, b_g,
                                                thetaT, phiT, gp);
  attn_k<<<dim3(1024), 256, 0, stream>>>(thetaT, phiT, gp, wo, b_o, x, gamma, out);
}

// Round 4
// 458.410 us; speedup vs baseline: 1.7193x; 1.1890x over previous
//
#include <hip/hip_runtime.h>
#include <cstdint>
#include <cstddef>

#define BB 16
#define CIN 512
#define NPIX 4096   // 64*64
#define C8 64
#define C2 256
#define MM 1024     // pooled positions 32*32

using bf16x8 = __attribute__((ext_vector_type(8))) short;
using f32x4  = __attribute__((ext_vector_type(4))) float;

__device__ __forceinline__ short f2bf(float f) {
  union { float f; unsigned u; } v; v.f = f;
  unsigned r = v.u + 0x7FFFu + ((v.u >> 16) & 1u);
  return (short)(r >> 16);
}
// packed f32x2 -> bf16x2 (RNE), single HW instr on gfx950
__device__ __forceinline__ unsigned cvtpk(float lo, float hi) {
  unsigned r;
  asm("v_cvt_pk_bf16_f32 %0, %1, %2" : "=v"(r) : "v"(lo), "v"(hi));
  return r;
}
__device__ __forceinline__ bf16x8 ldg8(const short* p) {
  return *reinterpret_cast<const bf16x8*>(p);
}
__device__ __forceinline__ bf16x8 lds8(const short* p) {  // 8B-aligned LDS read
  union { unsigned long long q[2]; bf16x8 v; } u;
  u.q[0] = *reinterpret_cast<const unsigned long long*>(p);
  u.q[1] = *reinterpret_cast<const unsigned long long*>(p + 4);
  return u.v;
}
#define MFMA(a, b, c) __builtin_amdgcn_mfma_f32_16x16x32_bf16(a, b, c, 0, 0, 0)
#define LOG2E 1.4426950408889634f

// ---------------------------------------------------------------------------
// weight casts: Wtheta(32768) | Wphi(32768) | Wg(131072) | Wo(131072) floats
// Wtheta pre-scaled by log2(e) so softmax can use raw exp2 (v_exp_f32).
// ---------------------------------------------------------------------------
__global__ __launch_bounds__(256) void cast_w_k(const float* __restrict__ wa,
                                                const float* __restrict__ wb,
                                                const float* __restrict__ wc,
                                                const float* __restrict__ wd,
                                                short* __restrict__ out) {
  int i = blockIdx.x * 256 + threadIdx.x;
  float v;
  if (i < 32768) v = wa[i] * LOG2E;
  else if (i < 65536) v = wb[i - 32768];
  else if (i < 196608) v = wc[i - 65536];
  else v = wd[i - 196608];
  out[i] = f2bf(v);
}

// ---------------------------------------------------------------------------
// conv_mega v5: 1024 threads (16 waves) per block -> 16 resident waves/CU
// (was 8: acc 96 AGPR + ~60 VGPR capped residency at one 8-wave block).
// Wave w: oc group (w&7)*48, pixel half wh=w>>3. Pixel halves are
// row-interleaved (half 0: cols [0,32) of both image rows; half 1: [32,64))
// so 2x2 pooling pairs stay intra-wave: acc[tt][j], j=row-bit<<1 | col-tile,
// vertical pair (j, j+2), horizontal via shfl_xor(,1).
// acc[3][4] = 48 AGPRs -> unified ~100 regs < 128 cap for 16 waves.
// ---------------------------------------------------------------------------
__global__ __launch_bounds__(1024) void conv_mega_k(
    const float* __restrict__ x, const short* __restrict__ wbf,
    const float* __restrict__ bth, const float* __restrict__ bph,
    const float* __restrict__ bg,
    short* __restrict__ thetaT, short* __restrict__ phiT,
    short* __restrict__ gp) {
  __shared__ __align__(16) short xs[128][36];   // stride 72B: 8B-aligned rows
  const int t = threadIdx.x, w = t >> 6, l = t & 63;
  const int lr = l & 15, quad = l >> 4;
  const int wg = w & 7, wh = w >> 3;
  const int bx = blockIdx.x, b = blockIdx.y;
  const int nbase = bx * 128;
  const float* xb = x + ((size_t)b * CIN << 12) + nbase;

  // staging: 128 px x 32 ch / 1024 thr = 4 values per thread
  const int nl = t & 127, cg = t >> 7;   // cg in 0..7

  f32x4 acc[3][4];
#pragma unroll
  for (int i = 0; i < 3; ++i)
#pragma unroll
    for (int j = 0; j < 4; ++j) acc[i][j] = (f32x4){0.f, 0.f, 0.f, 0.f};

  float pv0[2], pv1[2];
#pragma unroll
  for (int p = 0; p < 2; ++p) {
    int cl = (p * 8 + cg) * 2;
    pv0[p] = xb[((size_t)cl << 12) + nl];
    pv1[p] = xb[((size_t)(cl + 1) << 12) + nl];
  }

  for (int c0 = 0; c0 < CIN; c0 += 32) {
    // weight loads issued early: latency hides under barrier+staging
    bf16x8 af[3];
#pragma unroll
    for (int tt = 0; tt < 3; ++tt)
      af[tt] = ldg8(wbf + (size_t)(wg * 48 + tt * 16 + lr) * CIN + c0 + quad * 8);
    asm volatile("s_waitcnt lgkmcnt(0)" ::: "memory");
    __builtin_amdgcn_s_barrier();   // prev chunk's LDS reads complete (WAR)
#pragma unroll
    for (int p = 0; p < 2; ++p) {
      int cl = (p * 8 + cg) * 2;
      *reinterpret_cast<unsigned*>(&xs[nl][cl]) = cvtpk(pv0[p], pv1[p]);
    }
    asm volatile("s_waitcnt lgkmcnt(0)" ::: "memory");
    __builtin_amdgcn_s_barrier();   // xs visible
    if (c0 + 32 < CIN) {
#pragma unroll
      for (int p = 0; p < 2; ++p) {
        int cl = (p * 8 + cg) * 2;
        pv0[p] = xb[((size_t)(c0 + 32 + cl) << 12) + nl];
        pv1[p] = xb[((size_t)(c0 + 32 + cl + 1) << 12) + nl];
      }
    }
#pragma unroll
    for (int j = 0; j < 4; ++j) {
      const int gnt = (j & 1) + wh * 2 + (j >> 1) * 4;
      bf16x8 bfr = lds8(&xs[gnt * 16 + lr][quad * 8]);
#pragma unroll
      for (int tt = 0; tt < 3; ++tt)
        acc[tt][j] = MFMA(af[tt], bfr, acc[tt][j]);
    }
  }

#pragma unroll
  for (int tt = 0; tt < 3; ++tt) {
    const int ocb = wg * 48 + tt * 16;
    if (ocb < 64) {           // theta: no pool, (n, 64) layout, scaled by log2e
      short* tb = thetaT + ((size_t)b << 12) * C8;
#pragma unroll
      for (int r = 0; r < 4; ++r) {
        int oc = ocb + quad * 4 + r;
        float bia = bth[oc] * LOG2E;
#pragma unroll
        for (int j = 0; j < 4; ++j) {
          const int gnt = (j & 1) + wh * 2 + (j >> 1) * 4;
          int n = nbase + gnt * 16 + lr;
          tb[(size_t)n * C8 + oc] = f2bf(fmaxf(acc[tt][j][r] + bia, 0.f));
        }
      }
    } else if (ocb < 128) {   // phi: pool, (m, 64) layout
      short* pb = phiT + ((size_t)b << 10) * C8;
#pragma unroll
      for (int r = 0; r < 4; ++r) {
        int oc = ocb - 64 + quad * 4 + r;
        float bia = bph[oc];
#pragma unroll
        for (int jj = 0; jj < 2; ++jj) {
          float va = fmaxf(acc[tt][jj][r] + bia, 0.f);      // image row 0
          float vb = fmaxf(acc[tt][jj + 2][r] + bia, 0.f);  // image row 1
          float pa = fmaxf(va, __shfl_xor(va, 1));
          float pbv = fmaxf(vb, __shfl_xor(vb, 1));
          float pool = fmaxf(pa, pbv);
          if ((l & 1) == 0) {
            int m = bx * 32 + wh * 16 + jj * 8 + (lr >> 1);
            pb[(size_t)m * C8 + oc] = f2bf(pool);
          }
        }
      }
    } else {                  // g: pool, (256, 1024) c-major layout
      short* gb = gp + ((size_t)b << 10) * C2;
#pragma unroll
      for (int r = 0; r < 4; ++r) {
        int oc = ocb - 128 + quad * 4 + r;
        float bia = bg[oc];
#pragma unroll
        for (int jj = 0; jj < 2; ++jj) {
          float va = fmaxf(acc[tt][jj][r] + bia, 0.f);
          float vb = fmaxf(acc[tt][jj + 2][r] + bia, 0.f);
          float pa = fmaxf(va, __shfl_xor(va, 1));
          float pbv = fmaxf(vb, __shfl_xor(vb, 1));
          float pool = fmaxf(pa, pbv);
          if ((l & 1) == 0) {
            int m = bx * 32 + wh * 16 + jj * 8 + (lr >> 1);
            gb[(size_t)oc * MM + m] = f2bf(pool);
          }
        }
      }
    }
  }
}

// ---------------------------------------------------------------------------
// attn_k v5: v4 structure + explicit deep load batching. At 2 waves/SIMD the
// unified reg budget is 256/wave; v4 used ~180 (84 VGPR + ~96 AGPR) with the
// compiler dribbling loads 2-4 at a time. launch_bounds(256,2) makes the
// budget explicit; scores preload all 16 phi frags; PV rotates ga/pf one kc
// ahead; final conv preloads 8 wa frags per half-pass. nt hints reverted.
// ---------------------------------------------------------------------------
__global__ __launch_bounds__(256, 2) void attn_k(
    const short* __restrict__ thetaT, const short* __restrict__ phiT,
    const short* __restrict__ gp, const short* __restrict__ wo,
    const float* __restrict__ bo, const float* __restrict__ x,
    const float* __restrict__ gamma, float* __restrict__ out) {
  // ps[2][4][16][132] (33792B) unioned with os[64][264] (33792B)
  __shared__ __align__(16) short smem[16896];
  __shared__ float balpha[2][4][16];
  __shared__ float binv[4][16];
  const int t = threadIdx.x, w = t >> 6, l = t & 63;
  const int lr = l & 15, quad = l >> 4;
  const int blk = blockIdx.x;
  const int b = ((blk & 7) << 1) | ((blk >> 3) & 1);   // 2 batches per XCD
  const int q0 = (blk >> 4) << 6;
  const int nw = q0 + w * 16;

  const short* thb = thetaT + ((size_t)b << 12) * C8;
  const short* phb = phiT + ((size_t)b << 10) * C8;
  const short* gpb = gp + ((size_t)b << 10) * C2;

  bf16x8 tb0 = ldg8(thb + (size_t)(nw + lr) * C8 + quad * 8);
  bf16x8 tb1 = ldg8(thb + (size_t)(nw + lr) * C8 + 32 + quad * 8);

  f32x4 oacc[4][4];   // [ct][qt]: c = 64w+16ct+quad*4+r, n = q0+16qt+lr
#pragma unroll
  for (int i = 0; i < 4; ++i)
#pragma unroll
    for (int j = 0; j < 4; ++j) oacc[i][j] = (f32x4){0.f, 0.f, 0.f, 0.f};
  float mrun = -3e38f, ssum = 0.f;

  // scores+softmax for chunk ch -> ps[ch&1] quadrant w, balpha[ch&1][w]
  auto scores = [&](int ch) {
    const int m0 = ch * 128, buf = ch & 1;
    // batch all 16 phi loads -> 16 in flight before the MFMA chain
    bf16x8 ph0[8], ph1[8];
#pragma unroll
    for (int mt = 0; mt < 8; ++mt) {
      const short* pr = phb + (size_t)(m0 + mt * 16 + lr) * C8 + quad * 8;
      ph0[mt] = ldg8(pr);
      ph1[mt] = ldg8(pr + 32);
    }
    f32x4 sacc[8];
#pragma unroll
    for (int i = 0; i < 8; ++i) sacc[i] = (f32x4){0.f, 0.f, 0.f, 0.f};
#pragma unroll
    for (int mt = 0; mt < 8; ++mt) {
      sacc[mt] = MFMA(ph0[mt], tb0, sacc[mt]);
      sacc[mt] = MFMA(ph1[mt], tb1, sacc[mt]);
    }
    float cmax = sacc[0][0];
#pragma unroll
    for (int mt = 0; mt < 8; ++mt)
      cmax = fmaxf(cmax, fmaxf(fmaxf(sacc[mt][0], sacc[mt][1]),
                               fmaxf(sacc[mt][2], sacc[mt][3])));
    cmax = fmaxf(cmax, __shfl_xor(cmax, 16));
    cmax = fmaxf(cmax, __shfl_xor(cmax, 32));
    const float mnew = fmaxf(mrun, cmax);
    const float al = exp2f(mrun - mnew);   // exp2 domain (theta pre-scaled)
    mrun = mnew;
    float rsum = 0.f;
    short* prow = smem + ((((buf << 2) | w) << 4) + lr) * 132;
#pragma unroll
    for (int mt = 0; mt < 8; ++mt) {
      float e0 = exp2f(sacc[mt][0] - mnew);
      float e1 = exp2f(sacc[mt][1] - mnew);
      float e2 = exp2f(sacc[mt][2] - mnew);
      float e3 = exp2f(sacc[mt][3] - mnew);
      rsum += (e0 + e1) + (e2 + e3);
      uint2 pk2;
      pk2.x = cvtpk(e0, e1);
      pk2.y = cvtpk(e2, e3);
      *reinterpret_cast<uint2*>(prow + mt * 16 + quad * 4) = pk2;
    }
    ssum = ssum * al + rsum;
    if (quad == 0) balpha[buf][w][lr] = al;
  };

  bf16x8 gpf[4];   // kc0 ga prefetch: issued pre-barrier, consumed post
  auto pfga = [&](int ch) {
    const int m0 = ch * 128;
#pragma unroll
    for (int ct = 0; ct < 4; ++ct)
      gpf[ct] = ldg8(gpb + (size_t)(w * 64 + ct * 16 + lr) * MM + m0 + quad * 8);
  };

  scores(0);
  pfga(0);
  for (int ch = 0; ch < 8; ++ch) {
    const int buf = ch & 1, m0 = ch * 128;
    // raw barrier: drain LDS only; global loads (gpf) stay in flight
    asm volatile("s_waitcnt lgkmcnt(0)" ::: "memory");
    __builtin_amdgcn_s_barrier();
    float av[4];
#pragma unroll
    for (int qt = 0; qt < 4; ++qt) av[qt] = balpha[buf][qt][lr];
#pragma unroll
    for (int ct = 0; ct < 4; ++ct)
#pragma unroll
      for (int qt = 0; qt < 4; ++qt) oacc[ct][qt] *= av[qt];
    // PV: wave w covers c [64w, 64w+64), all 64 queries; ga/pf rotated 1 kc
    bf16x8 cga[4], cpf[4];
#pragma unroll
    for (int ct = 0; ct < 4; ++ct) cga[ct] = gpf[ct];
#pragma unroll
    for (int qt = 0; qt < 4; ++qt)
      cpf[qt] = lds8(smem + ((((buf << 2) | qt) << 4) + lr) * 132 + quad * 8);
#pragma unroll
    for (int kc = 0; kc < 4; ++kc) {
      bf16x8 nga[4], npf[4];
      if (kc < 3) {
#pragma unroll
        for (int ct = 0; ct < 4; ++ct)
          nga[ct] = ldg8(gpb + (size_t)(w * 64 + ct * 16 + lr) * MM +
                         m0 + (kc + 1) * 32 + quad * 8);
#pragma unroll
        for (int qt = 0; qt < 4; ++qt)
          npf[qt] = lds8(smem + ((((buf << 2) | qt) << 4) + lr) * 132 +
                         (kc + 1) * 32 + quad * 8);
      }
#pragma unroll
      for (int ct = 0; ct < 4; ++ct)
#pragma unroll
        for (int qt = 0; qt < 4; ++qt)
          oacc[ct][qt] = MFMA(cga[ct], cpf[qt], oacc[ct][qt]);
      if (kc < 3) {
#pragma unroll
        for (int i = 0; i < 4; ++i) { cga[i] = nga[i]; cpf[i] = npf[i]; }
      }
    }
    if (ch < 7) {
      scores(ch + 1);   // fills ps[!buf]; phi loads overlap PV above
      pfga(ch + 1);     // issued pre-barrier -> spans the raw barrier
    }
  }

  // ---- final softmax denominators ----
  ssum += __shfl_xor(ssum, 16);
  ssum += __shfl_xor(ssum, 32);
  if (quad == 0) binv[w][lr] = 1.f / ssum;
  __syncthreads();   // all PV/scores done (smem reusable as os), binv ready
  float invn[4];
#pragma unroll
  for (int qt = 0; qt < 4; ++qt) invn[qt] = binv[qt][lr];

  // ---- write o to LDS as (64 n x 256 c), rows n-local = 16qt+lr ----
  short (*os)[264] = reinterpret_cast<short (*)[264]>(smem);
#pragma unroll
  for (int ct = 0; ct < 4; ++ct) {
    int c0 = w * 64 + ct * 16 + quad * 4;
#pragma unroll
    for (int qt = 0; qt < 4; ++qt) {
      uint2 pk2;
      pk2.x = cvtpk(oacc[ct][qt][0] * invn[qt], oacc[ct][qt][1] * invn[qt]);
      pk2.y = cvtpk(oacc[ct][qt][2] * invn[qt], oacc[ct][qt][3] * invn[qt]);
      *reinterpret_cast<uint2*>(&os[qt * 16 + lr][c0]) = pk2;
    }
  }
  __syncthreads();   // os complete

  // ---- fused final conv: wave w -> oc [128w,+128) in 4 passes of 32 ----
  const float g0 = gamma[0];
  for (int pp = 0; pp < 4; ++pp) {
    const int ocb = w * 128 + pp * 32;
    f32x4 acc2[2][4];
#pragma unroll
    for (int i = 0; i < 2; ++i)
#pragma unroll
      for (int j = 0; j < 4; ++j) acc2[i][j] = (f32x4){0.f, 0.f, 0.f, 0.f};
#pragma unroll
    for (int half = 0; half < 2; ++half) {
      // batch 8 wa loads (4 kc x 2 ot) for this half
      bf16x8 wa[8];
#pragma unroll
      for (int k2 = 0; k2 < 4; ++k2)
#pragma unroll
        for (int ot = 0; ot < 2; ++ot)
          wa[k2 * 2 + ot] = ldg8(wo + (size_t)(ocb + ot * 16 + lr) * C2 +
                                 (half * 4 + k2) * 32 + quad * 8);
#pragma unroll
      for (int k2 = 0; k2 < 4; ++k2) {
        const int kc = half * 4 + k2;
        bf16x8 of[4];
#pragma unroll
        for (int qt = 0; qt < 4; ++qt)
          of[qt] = lds8(&os[qt * 16 + lr][kc * 32 + quad * 8]);
#pragma unroll
        for (int ot = 0; ot < 2; ++ot)
#pragma unroll
          for (int qt = 0; qt < 4; ++qt)
            acc2[ot][qt] = MFMA(wa[k2 * 2 + ot], of[qt], acc2[ot][qt]);
      }
    }
#pragma unroll
    for (int ot = 0; ot < 2; ++ot) {
#pragma unroll
      for (int r = 0; r < 4; ++r) {
        int oc = ocb + ot * 16 + quad * 4 + r;
        float bia = bo[oc];
        size_t base = ((size_t)(b * CIN + oc) << 12);
#pragma unroll
        for (int qt = 0; qt < 4; ++qt) {
          int n = q0 + qt * 16 + lr;
          float v = g0 * fmaxf(acc2[ot][qt][r] + bia, 0.f);
          out[base + n] = v + x[base + n];
        }
      }
    }
  }
}

// ---------------------------------------------------------------------------
extern "C" void kernel_launch(void* const* d_in, const int* in_sizes, int n_in,
                              void* d_out, int out_size, void* d_ws, size_t ws_size,
                              hipStream_t stream) {
  const float* x       = (const float*)d_in[0];
  const float* W_theta = (const float*)d_in[1];
  const float* b_theta = (const float*)d_in[2];
  const float* W_phi   = (const float*)d_in[3];
  const float* b_phi   = (const float*)d_in[4];
  const float* W_g     = (const float*)d_in[5];
  const float* b_g     = (const float*)d_in[6];
  const float* W_o     = (const float*)d_in[7];
  const float* b_o     = (const float*)d_in[8];
  const float* gamma   = (const float*)d_in[9];
  float* out = (float*)d_out;
  char* W = (char*)d_ws;

  // workspace (bytes): thetaT 8,388,608 | phiT 2,097,152 | gp 8,388,608 | wbf 655,360
  short* thetaT = (short*)(W);
  short* phiT   = (short*)(W + 8388608);
  short* gp     = (short*)(W + 10485760);
  short* wbf    = (short*)(W + 18874368);
  short* wo     = wbf + 196608;

  cast_w_k<<<dim3(1280), 256, 0, stream>>>(W_theta, W_phi, W_g, W_o, wbf);
  conv_mega_k<<<dim3(32, 16), 1024, 0, stream>>>(x, wbf, b_theta, b_phi, b_g,
                                                 thetaT, phiT, gp);
  attn_k<<<dim3(1024), 256, 0, stream>>>(thetaT, phiT, gp, wo, b_o, x, gamma, out);
}

// Round 5
// 401.103 us; speedup vs baseline: 1.9650x; 1.1429x over previous
//
#include <hip/hip_runtime.h>
#include <cstdint>
#include <cstddef>

#define BB 16
#define CIN 512
#define NPIX 4096   // 64*64
#define C8 64
#define C2 256
#define MM 1024     // pooled positions 32*32

using bf16x8 = __attribute__((ext_vector_type(8))) short;
using f32x4  = __attribute__((ext_vector_type(4))) float;

__device__ __forceinline__ short f2bf(float f) {
  union { float f; unsigned u; } v; v.f = f;
  unsigned r = v.u + 0x7FFFu + ((v.u >> 16) & 1u);
  return (short)(r >> 16);
}
// packed f32x2 -> bf16x2 (RNE), single HW instr on gfx950
__device__ __forceinline__ unsigned cvtpk(float lo, float hi) {
  unsigned r;
  asm("v_cvt_pk_bf16_f32 %0, %1, %2" : "=v"(r) : "v"(lo), "v"(hi));
  return r;
}
__device__ __forceinline__ bf16x8 ldg8(const short* p) {
  return *reinterpret_cast<const bf16x8*>(p);
}
__device__ __forceinline__ bf16x8 lds8(const short* p) {  // 8B-aligned LDS read
  union { unsigned long long q[2]; bf16x8 v; } u;
  u.q[0] = *reinterpret_cast<const unsigned long long*>(p);
  u.q[1] = *reinterpret_cast<const unsigned long long*>(p + 4);
  return u.v;
}
__device__ __forceinline__ void sts8(short* p, bf16x8 v) {  // 8B-aligned LDS write
  union { unsigned long long q[2]; bf16x8 v; } u; u.v = v;
  *reinterpret_cast<unsigned long long*>(p) = u.q[0];
  *reinterpret_cast<unsigned long long*>(p + 4) = u.q[1];
}
#define MFMA(a, b, c) __builtin_amdgcn_mfma_f32_16x16x32_bf16(a, b, c, 0, 0, 0)
#define LOG2E 1.4426950408889634f

// ---------------------------------------------------------------------------
// weight casts: Wtheta(32768) | Wphi(32768) | Wg(131072) | Wo(131072) floats
// Wtheta pre-scaled by log2(e) so softmax can use raw exp2 (v_exp_f32).
// ---------------------------------------------------------------------------
__global__ __launch_bounds__(256) void cast_w_k(const float* __restrict__ wa,
                                                const float* __restrict__ wb,
                                                const float* __restrict__ wc,
                                                const float* __restrict__ wd,
                                                short* __restrict__ out) {
  int i = blockIdx.x * 256 + threadIdx.x;
  float v;
  if (i < 32768) v = wa[i] * LOG2E;
  else if (i < 65536) v = wb[i - 32768];
  else if (i < 196608) v = wc[i - 65536];
  else v = wd[i - 196608];
  out[i] = f2bf(v);
}

// ---------------------------------------------------------------------------
// conv_mega v6: 1024 threads (16 waves). v5 + 2-chunk-deep x register
// prefetch (HBM ~900cy now spans 2 chunk periods instead of 1) + setprio
// around the MFMA cluster.
// ---------------------------------------------------------------------------
__global__ __launch_bounds__(1024) void conv_mega_k(
    const float* __restrict__ x, const short* __restrict__ wbf,
    const float* __restrict__ bth, const float* __restrict__ bph,
    const float* __restrict__ bg,
    short* __restrict__ thetaT, short* __restrict__ phiT,
    short* __restrict__ gp) {
  __shared__ __align__(16) short xs[128][36];   // stride 72B: 8B-aligned rows
  const int t = threadIdx.x, w = t >> 6, l = t & 63;
  const int lr = l & 15, quad = l >> 4;
  const int wg = w & 7, wh = w >> 3;
  const int bx = blockIdx.x, b = blockIdx.y;
  const int nbase = bx * 128;
  const float* xb = x + ((size_t)b * CIN << 12) + nbase;

  // staging: 128 px x 32 ch / 1024 thr = 4 values per thread per chunk
  const int nl = t & 127, cg = t >> 7;   // cg in 0..7

  f32x4 acc[3][4];
#pragma unroll
  for (int i = 0; i < 3; ++i)
#pragma unroll
    for (int j = 0; j < 4; ++j) acc[i][j] = (f32x4){0.f, 0.f, 0.f, 0.f};

  // 2-deep prefetch: slot s holds chunk (c0/32) with (c0>>5)&1 == s
  float pv0[2][2], pv1[2][2];
#pragma unroll
  for (int s = 0; s < 2; ++s)
#pragma unroll
    for (int p = 0; p < 2; ++p) {
      int cl = s * 32 + (p * 8 + cg) * 2;
      pv0[s][p] = xb[((size_t)cl << 12) + nl];
      pv1[s][p] = xb[((size_t)(cl + 1) << 12) + nl];
    }

  for (int c0 = 0; c0 < CIN; c0 += 32) {
    const int slot = (c0 >> 5) & 1;
    // weight loads issued early: latency hides under barrier+staging
    bf16x8 af[3];
#pragma unroll
    for (int tt = 0; tt < 3; ++tt)
      af[tt] = ldg8(wbf + (size_t)(wg * 48 + tt * 16 + lr) * CIN + c0 + quad * 8);
    asm volatile("s_waitcnt lgkmcnt(0)" ::: "memory");
    __builtin_amdgcn_s_barrier();   // prev chunk's LDS reads complete (WAR)
#pragma unroll
    for (int p = 0; p < 2; ++p) {
      int cl = (p * 8 + cg) * 2;
      *reinterpret_cast<unsigned*>(&xs[nl][cl]) = cvtpk(pv0[slot][p], pv1[slot][p]);
    }
    asm volatile("s_waitcnt lgkmcnt(0)" ::: "memory");
    __builtin_amdgcn_s_barrier();   // xs visible
    if (c0 + 64 < CIN) {
#pragma unroll
      for (int p = 0; p < 2; ++p) {
        int cl = (p * 8 + cg) * 2;
        pv0[slot][p] = xb[((size_t)(c0 + 64 + cl) << 12) + nl];
        pv1[slot][p] = xb[((size_t)(c0 + 64 + cl + 1) << 12) + nl];
      }
    }
    __builtin_amdgcn_s_setprio(1);
#pragma unroll
    for (int j = 0; j < 4; ++j) {
      const int gnt = (j & 1) + wh * 2 + (j >> 1) * 4;
      bf16x8 bfr = lds8(&xs[gnt * 16 + lr][quad * 8]);
#pragma unroll
      for (int tt = 0; tt < 3; ++tt)
        acc[tt][j] = MFMA(af[tt], bfr, acc[tt][j]);
    }
    __builtin_amdgcn_s_setprio(0);
  }

#pragma unroll
  for (int tt = 0; tt < 3; ++tt) {
    const int ocb = wg * 48 + tt * 16;
    if (ocb < 64) {           // theta: no pool, (n, 64) layout, scaled by log2e
      short* tb = thetaT + ((size_t)b << 12) * C8;
#pragma unroll
      for (int r = 0; r < 4; ++r) {
        int oc = ocb + quad * 4 + r;
        float bia = bth[oc] * LOG2E;
#pragma unroll
        for (int j = 0; j < 4; ++j) {
          const int gnt = (j & 1) + wh * 2 + (j >> 1) * 4;
          int n = nbase + gnt * 16 + lr;
          tb[(size_t)n * C8 + oc] = f2bf(fmaxf(acc[tt][j][r] + bia, 0.f));
        }
      }
    } else if (ocb < 128) {   // phi: pool, (m, 64) layout
      short* pb = phiT + ((size_t)b << 10) * C8;
#pragma unroll
      for (int r = 0; r < 4; ++r) {
        int oc = ocb - 64 + quad * 4 + r;
        float bia = bph[oc];
#pragma unroll
        for (int jj = 0; jj < 2; ++jj) {
          float va = fmaxf(acc[tt][jj][r] + bia, 0.f);      // image row 0
          float vb = fmaxf(acc[tt][jj + 2][r] + bia, 0.f);  // image row 1
          float pa = fmaxf(va, __shfl_xor(va, 1));
          float pbv = fmaxf(vb, __shfl_xor(vb, 1));
          float pool = fmaxf(pa, pbv);
          if ((l & 1) == 0) {
            int m = bx * 32 + wh * 16 + jj * 8 + (lr >> 1);
            pb[(size_t)m * C8 + oc] = f2bf(pool);
          }
        }
      }
    } else {                  // g: pool, (256, 1024) c-major layout
      short* gb = gp + ((size_t)b << 10) * C2;
#pragma unroll
      for (int r = 0; r < 4; ++r) {
        int oc = ocb - 128 + quad * 4 + r;
        float bia = bg[oc];
#pragma unroll
        for (int jj = 0; jj < 2; ++jj) {
          float va = fmaxf(acc[tt][jj][r] + bia, 0.f);
          float vb = fmaxf(acc[tt][jj + 2][r] + bia, 0.f);
          float pa = fmaxf(va, __shfl_xor(va, 1));
          float pbv = fmaxf(vb, __shfl_xor(vb, 1));
          float pool = fmaxf(pa, pbv);
          if ((l & 1) == 0) {
            int m = bx * 32 + wh * 16 + jj * 8 + (lr >> 1);
            gb[(size_t)oc * MM + m] = f2bf(pool);
          }
        }
      }
    }
  }
}

// ---------------------------------------------------------------------------
// attn_k v6: v5 + (a) phi chunk staged ONCE per block into LDS (was: all 4
// waves redundantly loading the identical 16KB -> 4x L2 traffic + 64 VGPRs
// for the batch); freed regs go to (b) full-chunk ga prefetch gpf[16] issued
// pre-barrier, so PV never waits on global; (c) defer-max (THR=8, exp2
// domain): running max kept unless it grows >8, so alpha==1 and the 64-mul
// oacc rescale is skipped via a wave-uniform branch most chunks; (d)
// s_setprio(1) around MFMA clusters.
// Two raw barriers per chunk: b1 = ps[buf]+balpha ready / phi buffer free;
// b2 = phi(ch+1) staged. ga/phi-stage loads stay in flight across both.
// ---------------------------------------------------------------------------
__global__ __launch_bounds__(256, 2) void attn_k(
    const short* __restrict__ thetaT, const short* __restrict__ phiT,
    const short* __restrict__ gp, const short* __restrict__ wo,
    const float* __restrict__ bo, const float* __restrict__ x,
    const float* __restrict__ gamma, float* __restrict__ out) {
  // ps[2][4][16][132] (33792 shorts) unioned with os[64][264]
  __shared__ __align__(16) short smem[16896];
  __shared__ __align__(16) short phs[128][68];   // phi chunk 128m x 64c, pad->68
  __shared__ float balpha[2][4][16];
  __shared__ float binv[4][16];
  const int t = threadIdx.x, w = t >> 6, l = t & 63;
  const int lr = l & 15, quad = l >> 4;
  const int blk = blockIdx.x;
  const int b = ((blk & 7) << 1) | ((blk >> 3) & 1);   // 2 batches per XCD
  const int q0 = (blk >> 4) << 6;
  const int nw = q0 + w * 16;

  const short* thb = thetaT + ((size_t)b << 12) * C8;
  const short* phb = phiT + ((size_t)b << 10) * C8;
  const short* gpb = gp + ((size_t)b << 10) * C2;

  bf16x8 tb0 = ldg8(thb + (size_t)(nw + lr) * C8 + quad * 8);
  bf16x8 tb1 = ldg8(thb + (size_t)(nw + lr) * C8 + 32 + quad * 8);

  f32x4 oacc[4][4];   // [ct][qt]: c = 64w+16ct+quad*4+r, n = q0+16qt+lr
#pragma unroll
  for (int i = 0; i < 4; ++i)
#pragma unroll
    for (int j = 0; j < 4; ++j) oacc[i][j] = (f32x4){0.f, 0.f, 0.f, 0.f};
  float mrun = -3e38f, ssum = 0.f;

  // cooperative phi staging: thread t covers rows sw*32 + (t>>3), col (t&7)*8
  const int srow = t >> 3, scol = (t & 7) * 8;
  bf16x8 stld[4];
  auto stage_phi_issue = [&](int ch) {
    const int m0 = ch * 128;
#pragma unroll
    for (int sw = 0; sw < 4; ++sw)
      stld[sw] = ldg8(phb + (size_t)(m0 + sw * 32 + srow) * C8 + scol);
  };
  auto stage_phi_write = [&]() {
#pragma unroll
    for (int sw = 0; sw < 4; ++sw)
      sts8(&phs[sw * 32 + srow][scol], stld[sw]);
  };

  // scores+softmax for chunk ch (phi from LDS) -> ps[ch&1], balpha[ch&1]
  auto scores = [&](int ch) {
    const int buf = ch & 1;
    f32x4 sacc[8];
#pragma unroll
    for (int i = 0; i < 8; ++i) sacc[i] = (f32x4){0.f, 0.f, 0.f, 0.f};
    __builtin_amdgcn_s_setprio(1);
#pragma unroll
    for (int mt = 0; mt < 8; ++mt) {
      const short* pr = &phs[mt * 16 + lr][quad * 8];
      sacc[mt] = MFMA(lds8(pr), tb0, sacc[mt]);
      sacc[mt] = MFMA(lds8(pr + 32), tb1, sacc[mt]);
    }
    __builtin_amdgcn_s_setprio(0);
    float cmax = sacc[0][0];
#pragma unroll
    for (int mt = 0; mt < 8; ++mt)
      cmax = fmaxf(cmax, fmaxf(fmaxf(sacc[mt][0], sacc[mt][1]),
                               fmaxf(sacc[mt][2], sacc[mt][3])));
    cmax = fmaxf(cmax, __shfl_xor(cmax, 16));
    cmax = fmaxf(cmax, __shfl_xor(cmax, 32));
    // defer-max: keep mrun unless max grew >8 (P bounded by 2^8, f32-safe)
    const float mnew = (cmax > mrun + 8.f) ? cmax : mrun;
    const float al = exp2f(mrun - mnew);   // == 1.0f when deferred
    mrun = mnew;
    float rsum = 0.f;
    short* prow = smem + ((((buf << 2) | w) << 4) + lr) * 132;
#pragma unroll
    for (int mt = 0; mt < 8; ++mt) {
      float e0 = exp2f(sacc[mt][0] - mnew);
      float e1 = exp2f(sacc[mt][1] - mnew);
      float e2 = exp2f(sacc[mt][2] - mnew);
      float e3 = exp2f(sacc[mt][3] - mnew);
      rsum += (e0 + e1) + (e2 + e3);
      uint2 pk2;
      pk2.x = cvtpk(e0, e1);
      pk2.y = cvtpk(e2, e3);
      *reinterpret_cast<uint2*>(prow + mt * 16 + quad * 4) = pk2;
    }
    ssum = ssum * al + rsum;
    if (quad == 0) balpha[buf][w][lr] = al;
  };

  // full-chunk ga prefetch (16 frags, issued pre-barrier, spans b1)
  bf16x8 gpf[16];
  auto pfga = [&](int ch) {
    const int m0 = ch * 128;
#pragma unroll
    for (int kc = 0; kc < 4; ++kc)
#pragma unroll
      for (int ct = 0; ct < 4; ++ct)
        gpf[kc * 4 + ct] = ldg8(gpb + (size_t)(w * 64 + ct * 16 + lr) * MM +
                                m0 + kc * 32 + quad * 8);
  };

  // prologue: stage phi(0), scores(0), prefetch ga(0)
  stage_phi_issue(0);
  stage_phi_write();
  asm volatile("s_waitcnt lgkmcnt(0)" ::: "memory");
  __builtin_amdgcn_s_barrier();   // phi(0) visible
  scores(0);
  pfga(0);

  for (int ch = 0; ch < 8; ++ch) {
    const int buf = ch & 1;
    asm volatile("s_waitcnt lgkmcnt(0)" ::: "memory");
    __builtin_amdgcn_s_barrier();   // b1: ps[buf]+balpha ready; phs free
    if (ch < 7) stage_phi_issue(ch + 1);   // global loads fly over PV
    float av[4];
#pragma unroll
    for (int qt = 0; qt < 4; ++qt) av[qt] = balpha[buf][qt][lr];
    if (av[0] != 1.f || av[1] != 1.f || av[2] != 1.f || av[3] != 1.f) {
#pragma unroll
      for (int ct = 0; ct < 4; ++ct)
#pragma unroll
        for (int qt = 0; qt < 4; ++qt) oacc[ct][qt] *= av[qt];
    }
    // PV: wave w covers c [64w, 64w+64), all 64 queries, ga pre-fetched
    __builtin_amdgcn_s_setprio(1);
#pragma unroll
    for (int kc = 0; kc < 4; ++kc) {
      bf16x8 pf[4];
#pragma unroll
      for (int qt = 0; qt < 4; ++qt)
        pf[qt] = lds8(smem + ((((buf << 2) | qt) << 4) + lr) * 132 +
                      kc * 32 + quad * 8);
#pragma unroll
      for (int ct = 0; ct < 4; ++ct)
#pragma unroll
        for (int qt = 0; qt < 4; ++qt)
          oacc[ct][qt] = MFMA(gpf[kc * 4 + ct], pf[qt], oacc[ct][qt]);
    }
    __builtin_amdgcn_s_setprio(0);
    if (ch < 7) {
      stage_phi_write();              // waits its 4 loads, writes phs
      asm volatile("s_waitcnt lgkmcnt(0)" ::: "memory");
      __builtin_amdgcn_s_barrier();   // b2: phi(ch+1) visible
      scores(ch + 1);                 // reads phs, writes ps[!buf]
      pfga(ch + 1);                   // spans next b1
    }
  }

  // ---- final softmax denominators ----
  ssum += __shfl_xor(ssum, 16);
  ssum += __shfl_xor(ssum, 32);
  if (quad == 0) binv[w][lr] = 1.f / ssum;
  __syncthreads();   // all PV/scores done (smem reusable as os), binv ready
  float invn[4];
#pragma unroll
  for (int qt = 0; qt < 4; ++qt) invn[qt] = binv[qt][lr];

  // ---- write o to LDS as (64 n x 256 c), rows n-local = 16qt+lr ----
  short (*os)[264] = reinterpret_cast<short (*)[264]>(smem);
#pragma unroll
  for (int ct = 0; ct < 4; ++ct) {
    int c0 = w * 64 + ct * 16 + quad * 4;
#pragma unroll
    for (int qt = 0; qt < 4; ++qt) {
      uint2 pk2;
      pk2.x = cvtpk(oacc[ct][qt][0] * invn[qt], oacc[ct][qt][1] * invn[qt]);
      pk2.y = cvtpk(oacc[ct][qt][2] * invn[qt], oacc[ct][qt][3] * invn[qt]);
      *reinterpret_cast<uint2*>(&os[qt * 16 + lr][c0]) = pk2;
    }
  }
  __syncthreads();   // os complete

  // ---- fused final conv: wave w -> oc [128w,+128) in 4 passes of 32 ----
  const float g0 = gamma[0];
  for (int pp = 0; pp < 4; ++pp) {
    const int ocb = w * 128 + pp * 32;
    f32x4 acc2[2][4];
#pragma unroll
    for (int i = 0; i < 2; ++i)
#pragma unroll
      for (int j = 0; j < 4; ++j) acc2[i][j] = (f32x4){0.f, 0.f, 0.f, 0.f};
#pragma unroll
    for (int half = 0; half < 2; ++half) {
      // batch 8 wa loads (4 kc x 2 ot) for this half
      bf16x8 wa[8];
#pragma unroll
      for (int k2 = 0; k2 < 4; ++k2)
#pragma unroll
        for (int ot = 0; ot < 2; ++ot)
          wa[k2 * 2 + ot] = ldg8(wo + (size_t)(ocb + ot * 16 + lr) * C2 +
                                 (half * 4 + k2) * 32 + quad * 8);
      __builtin_amdgcn_s_setprio(1);
#pragma unroll
      for (int k2 = 0; k2 < 4; ++k2) {
        const int kc = half * 4 + k2;
        bf16x8 of[4];
#pragma unroll
        for (int qt = 0; qt < 4; ++qt)
          of[qt] = lds8(&os[qt * 16 + lr][kc * 32 + quad * 8]);
#pragma unroll
        for (int ot = 0; ot < 2; ++ot)
#pragma unroll
          for (int qt = 0; qt < 4; ++qt)
            acc2[ot][qt] = MFMA(wa[k2 * 2 + ot], of[qt], acc2[ot][qt]);
      }
      __builtin_amdgcn_s_setprio(0);
    }
#pragma unroll
    for (int ot = 0; ot < 2; ++ot) {
#pragma unroll
      for (int r = 0; r < 4; ++r) {
        int oc = ocb + ot * 16 + quad * 4 + r;
        float bia = bo[oc];
        size_t base = ((size_t)(b * CIN + oc) << 12);
#pragma unroll
        for (int qt = 0; qt < 4; ++qt) {
          int n = q0 + qt * 16 + lr;
          float v = g0 * fmaxf(acc2[ot][qt][r] + bia, 0.f);
          out[base + n] = v + x[base + n];
        }
      }
    }
  }
}

// ---------------------------------------------------------------------------
extern "C" void kernel_launch(void* const* d_in, const int* in_sizes, int n_in,
                              void* d_out, int out_size, void* d_ws, size_t ws_size,
                              hipStream_t stream) {
  const float* x       = (const float*)d_in[0];
  const float* W_theta = (const float*)d_in[1];
  const float* b_theta = (const float*)d_in[2];
  const float* W_phi   = (const float*)d_in[3];
  const float* b_phi   = (const float*)d_in[4];
  const float* W_g     = (const float*)d_in[5];
  const float* b_g     = (const float*)d_in[6];
  const float* W_o     = (const float*)d_in[7];
  const float* b_o     = (const float*)d_in[8];
  const float* gamma   = (const float*)d_in[9];
  float* out = (float*)d_out;
  char* W = (char*)d_ws;

  // workspace (bytes): thetaT 8,388,608 | phiT 2,097,152 | gp 8,388,608 | wbf 655,360
  short* thetaT = (short*)(W);
  short* phiT   = (short*)(W + 8388608);
  short* gp     = (short*)(W + 10485760);
  short* wbf    = (short*)(W + 18874368);
  short* wo     = wbf + 196608;

  cast_w_k<<<dim3(1280), 256, 0, stream>>>(W_theta, W_phi, W_g, W_o, wbf);
  conv_mega_k<<<dim3(32, 16), 1024, 0, stream>>>(x, wbf, b_theta, b_phi, b_g,
                                                 thetaT, phiT, gp);
  attn_k<<<dim3(1024), 256, 0, stream>>>(thetaT, phiT, gp, wo, b_o, x, gamma, out);
}